// Round 7
// baseline (128.126 us; speedup 1.0000x reference)
//
#include <hip/hip_runtime.h>

// Soft VQ encoding, fused bf16-MFMA implementation. Round 7.
//   X:(8,16384,128) fp32, C:(128,128) fp32, S:(128) fp32 -> E:(8,128,128) fp32
// r6: dur 115us = ~70us fixed harness overhead (ws 0xAA fills @41us + d_in
// restore, visible in rocprof) + vq_main ~38 + reduce ~6. r7 attacks vq_main's
// LDS pipe (dominant: ~1050cyc/wave/chunk + 2.2M conflict cycles):
//   (1) sXT/sAt: unpadded + 16B-granule XOR swizzle (addr = row*64 +
//       (((n>>3)^((row>>3)&7))*8) + (n&7)). Old pad-72 layout put all 4 quads
//       of a scatter write on the same banks (8-row spacing x 36dw = 0 mod 32)
//       -> 4-way conflicts; swizzle makes writes AND frag reads <=2-way (free).
//   (2) hoist C-fragments for ks=0,1 into 64 VGPRs outside the t-loop ->
//       matmul1 ds_read_b128 count halved (32->16). Budget: ~160 arch + 72
//       acc = 232 < 256 cap (launch_bounds(256,2)). WRITE>20MB = spill tripwire.
//   (3) no-max softmax: S=-uniform(0,1) => D=S*L2<=0 => exp in (0,1], no
//       overflow; removes the max pass + 2 cross-lane ops per chunk.
// 2 kernels: vq_main<<<512,256>>> (TT=4 chunks of 64 rows, bf16 partials to
// private ws slices), vq_reduce<<<128,256>>> (fp32-sum 64 partials -> d_out).

#define NN   16384
#define ND   128
#define NK   128
#define NC   64        // rows per chunk
#define TT   4         // chunks per block
#define BPB  64        // blocks per batch (grid = 8*BPB = 512)
#define CBP  136       // sCb row stride (bf16 elems), 272B -> b128-aligned, 2-way banks

typedef __bf16 bf16x8 __attribute__((ext_vector_type(8)));
typedef float  f32x4  __attribute__((ext_vector_type(4)));

union CU  { __bf16 b[8]; unsigned short u[8]; bf16x8 v; };
union HH4 { __bf16 b[4]; ushort4 s; };

__device__ __forceinline__ float bf2f(unsigned short u) {
    return __uint_as_float(((unsigned int)u) << 16);
}

// ---------------- kernel 1: fused main ----------------
__global__ __launch_bounds__(256, 2) void vq_main(
    const float* __restrict__ Xg, const float* __restrict__ Cg,
    const float* __restrict__ Sg, unsigned short* __restrict__ Pg)
{
    __shared__ __align__(16) unsigned short sCb[NK * CBP];   // 34816 B
    __shared__ __align__(16) unsigned short sXT[ND * 64];    // 16384 B (swizzled)
    __shared__ __align__(16) unsigned short sAt[NK * 64];    // 16384 B (swizzled)
    __shared__ __align__(16) float2 sST[NK];                 // 1 KB
    __shared__ __align__(16) float  sC2[NK];                 // 512 B

    const int tid  = threadIdx.x;
    const int lane = tid & 63;
    const int wave = tid >> 6;
    const int l15  = lane & 15;
    const int quad = lane >> 4;
    const int bid  = blockIdx.x;
    const int b    = bid >> 6;        // batch
    const int bg   = bid & (BPB - 1); // block-in-batch

    // ---- prologue: stage C -> bf16 LDS, C2 row sums, ST = {S, S*C2} ----
    #pragma unroll
    for (int it = 0; it < 16; ++it) {
        int flat = it * 256 + tid;
        int row  = flat >> 5;          // 0..127
        int c4   = flat & 31;
        float4 v = reinterpret_cast<const float4*>(Cg)[row * 32 + c4];
        HH4 h;
        h.b[0] = (__bf16)v.x; h.b[1] = (__bf16)v.y;
        h.b[2] = (__bf16)v.z; h.b[3] = (__bf16)v.w;
        *reinterpret_cast<ushort4*>(&sCb[row * CBP + c4 * 4]) = h.s;
        float ss = v.x*v.x + v.y*v.y + v.z*v.z + v.w*v.w;
        ss += __shfl_xor(ss, 1);
        ss += __shfl_xor(ss, 2);
        ss += __shfl_xor(ss, 4);
        ss += __shfl_xor(ss, 8);
        ss += __shfl_xor(ss, 16);
        if ((lane & 31) == 0) sC2[row] = ss;
    }
    __syncthreads();
    if (tid < NK) {
        float s = Sg[tid];
        sST[tid] = make_float2(s, s * sC2[tid]);
    }
    // (barrier (A) of chunk 0 orders sST before first softmax use)

    // ---- hoist C-fragments for ks=0,1 (d<64): 16 x bf16x8 = 64 VGPRs ----
    bf16x8 chs[8][2];
    #pragma unroll
    for (int mt = 0; mt < 8; ++mt)
        #pragma unroll
        for (int ks = 0; ks < 2; ++ks)
            chs[mt][ks] = *reinterpret_cast<const bf16x8*>(
                &sCb[(mt * 16 + l15) * CBP + ks * 32 + quad * 8]);

    f32x4 eacc[2][8];
    #pragma unroll
    for (int i = 0; i < 2; ++i)
        #pragma unroll
        for (int j = 0; j < 8; ++j)
            eacc[i][j] = (f32x4){0.f, 0.f, 0.f, 0.f};
    f32x4 cntacc[2];
    cntacc[0] = (f32x4){0.f, 0.f, 0.f, 0.f};
    cntacc[1] = (f32x4){0.f, 0.f, 0.f, 0.f};

    CU one8;
    #pragma unroll
    for (int j = 0; j < 8; ++j) one8.u[j] = 0x3F80;  // bf16 1.0

    const float* Xb = Xg + (size_t)b * (NN * ND);
    const int rloc = wave * 16 + l15;   // chunk-local row this lane stages
    const int rg   = rloc >> 3;         // lane's n-granule
    const int rlow = rloc & 7;

    // software pipeline: raw[] holds next chunk's ks=0,1 halves (4 float4)
    float4 raw[4];
    {
        const float* rp0 = Xb + (size_t)(bg * TT * NC + rloc) * ND;
        raw[0] = *reinterpret_cast<const float4*>(rp0 + quad * 8);
        raw[1] = *reinterpret_cast<const float4*>(rp0 + quad * 8 + 4);
        raw[2] = *reinterpret_cast<const float4*>(rp0 + 32 + quad * 8);
        raw[3] = *reinterpret_cast<const float4*>(rp0 + 32 + quad * 8 + 4);
    }

    #pragma unroll 1
    for (int t = 0; t < TT; ++t) {
        const int chunk = bg * TT + t;
        const float* rp = Xb + (size_t)(chunk * NC + rloc) * ND;

        // ---- ks=2,3 loads issued first (latency overlapped w/ conversions) ----
        float4 va2 = *reinterpret_cast<const float4*>(rp + 64 + quad * 8);
        float4 vb2 = *reinterpret_cast<const float4*>(rp + 64 + quad * 8 + 4);
        float4 va3 = *reinterpret_cast<const float4*>(rp + 96 + quad * 8);
        float4 vb3 = *reinterpret_cast<const float4*>(rp + 96 + quad * 8 + 4);

        CU cu[4];
        float x2 = 0.f;
        #pragma unroll
        for (int ks = 0; ks < 2; ++ks) {
            float4 va = raw[ks * 2], vb = raw[ks * 2 + 1];
            x2 += va.x*va.x + va.y*va.y + va.z*va.z + va.w*va.w;
            x2 += vb.x*vb.x + vb.y*vb.y + vb.z*vb.z + vb.w*vb.w;
            cu[ks].b[0] = (__bf16)va.x; cu[ks].b[1] = (__bf16)va.y;
            cu[ks].b[2] = (__bf16)va.z; cu[ks].b[3] = (__bf16)va.w;
            cu[ks].b[4] = (__bf16)vb.x; cu[ks].b[5] = (__bf16)vb.y;
            cu[ks].b[6] = (__bf16)vb.z; cu[ks].b[7] = (__bf16)vb.w;
        }
        {
            x2 += va2.x*va2.x + va2.y*va2.y + va2.z*va2.z + va2.w*va2.w;
            x2 += vb2.x*vb2.x + vb2.y*vb2.y + vb2.z*vb2.z + vb2.w*vb2.w;
            cu[2].b[0] = (__bf16)va2.x; cu[2].b[1] = (__bf16)va2.y;
            cu[2].b[2] = (__bf16)va2.z; cu[2].b[3] = (__bf16)va2.w;
            cu[2].b[4] = (__bf16)vb2.x; cu[2].b[5] = (__bf16)vb2.y;
            cu[2].b[6] = (__bf16)vb2.z; cu[2].b[7] = (__bf16)vb2.w;
            x2 += va3.x*va3.x + va3.y*va3.y + va3.z*va3.z + va3.w*va3.w;
            x2 += vb3.x*vb3.x + vb3.y*vb3.y + vb3.z*vb3.z + vb3.w*vb3.w;
            cu[3].b[0] = (__bf16)va3.x; cu[3].b[1] = (__bf16)va3.y;
            cu[3].b[2] = (__bf16)va3.z; cu[3].b[3] = (__bf16)va3.w;
            cu[3].b[4] = (__bf16)vb3.x; cu[3].b[5] = (__bf16)vb3.y;
            cu[3].b[6] = (__bf16)vb3.z; cu[3].b[7] = (__bf16)vb3.w;
        }
        x2 += __shfl_xor(x2, 16);
        x2 += __shfl_xor(x2, 32);       // full X2 of row (chunk*64 + rloc)

        __syncthreads();                // (A) prev chunk's matmul2 reads done

        // ---- prefetch next chunk's ks=0,1 (in flight until barrier B) ----
        if (t + 1 < TT) {
            const float* rpn = rp + (size_t)NC * ND;
            raw[0] = *reinterpret_cast<const float4*>(rpn + quad * 8);
            raw[1] = *reinterpret_cast<const float4*>(rpn + quad * 8 + 4);
            raw[2] = *reinterpret_cast<const float4*>(rpn + 32 + quad * 8);
            raw[3] = *reinterpret_cast<const float4*>(rpn + 32 + quad * 8 + 4);
        }

        // ---- scatter X^T, granule-swizzled: addr = d*64 + (g^((d>>3)&7))*8 + n&7
        #pragma unroll
        for (int ks = 0; ks < 4; ++ks) {
            const int gx = (rg ^ (ks * 4 + quad)) & 7;   // (d>>3)&7 = (ks*4+quad)&7
            #pragma unroll
            for (int j = 0; j < 8; ++j) {
                int d = ks * 32 + quad * 8 + j;
                sXT[d * 64 + gx * 8 + rlow] = cu[ks].u[j];
            }
        }

        // ---- matmul1: DT[cw][n] = C x X^T (ks=0,1 from regs; ks=2,3 from LDS)
        f32x4 dacc[8];
        #pragma unroll
        for (int mt = 0; mt < 8; ++mt) {
            f32x4 acc = (f32x4){0.f, 0.f, 0.f, 0.f};
            acc = __builtin_amdgcn_mfma_f32_16x16x32_bf16(chs[mt][0], cu[0].v, acc, 0, 0, 0);
            acc = __builtin_amdgcn_mfma_f32_16x16x32_bf16(chs[mt][1], cu[1].v, acc, 0, 0, 0);
            #pragma unroll
            for (int ks = 2; ks < 4; ++ks) {
                bf16x8 af = *reinterpret_cast<const bf16x8*>(
                    &sCb[(mt * 16 + l15) * CBP + ks * 32 + quad * 8]);
                acc = __builtin_amdgcn_mfma_f32_16x16x32_bf16(af, cu[ks].v, acc, 0, 0, 0);
            }
            dacc[mt] = acc;
        }

        // ---- softmax over cw, NO max pass (S<=0 => D<=0 => exp in (0,1]) ----
        float ls = 0.f;
        #pragma unroll
        for (int mt = 0; mt < 8; ++mt) {
            float4 s01 = *reinterpret_cast<const float4*>(&sST[mt * 16 + quad * 4]);
            float4 s23 = *reinterpret_cast<const float4*>(&sST[mt * 16 + quad * 4 + 2]);
            float e0 = __expf(s01.x * fmaf(-2.f, dacc[mt][0], x2) + s01.y);
            float e1 = __expf(s01.z * fmaf(-2.f, dacc[mt][1], x2) + s01.w);
            float e2 = __expf(s23.x * fmaf(-2.f, dacc[mt][2], x2) + s23.y);
            float e3 = __expf(s23.z * fmaf(-2.f, dacc[mt][3], x2) + s23.w);
            dacc[mt][0] = e0; dacc[mt][1] = e1;
            dacc[mt][2] = e2; dacc[mt][3] = e3;
            ls += (e0 + e1) + (e2 + e3);
        }
        ls += __shfl_xor(ls, 16);
        ls += __shfl_xor(ls, 32);
        const float inv = 1.0f / ls;

        // ---- A -> LDS (A-layout rows=cw, cols=n), granule-swizzled ----
        #pragma unroll
        for (int mt = 0; mt < 8; ++mt) {
            #pragma unroll
            for (int r = 0; r < 4; ++r) {
                float a = dacc[mt][r] * inv;
                const int cw = mt * 16 + quad * 4 + r;
                const int gx = (rg ^ (cw >> 3)) & 7;
                *reinterpret_cast<__bf16*>(
                    &sAt[cw * 64 + gx * 8 + rlow]) = (__bf16)a;
            }
        }

        __syncthreads();                // (B) X^T and A^T visible to all waves

        // ---- matmul2: E[cw][d] += A x X ; counts via ones-column MFMA ----
        #pragma unroll
        for (int mt2 = 0; mt2 < 2; ++mt2) {
            const int cwrow = wave * 32 + mt2 * 16 + l15;
            const int cx = (cwrow >> 3) & 7;
            bf16x8 a0 = *reinterpret_cast<const bf16x8*>(
                &sAt[cwrow * 64 + ((quad ^ cx) & 7) * 8]);
            bf16x8 a1 = *reinterpret_cast<const bf16x8*>(
                &sAt[cwrow * 64 + (((4 + quad) ^ cx) & 7) * 8]);
            // count[cw] += sum_n A[cw][n]: B = ones -> D[row][col] indep of col
            cntacc[mt2] = __builtin_amdgcn_mfma_f32_16x16x32_bf16(a0, one8.v, cntacc[mt2], 0, 0, 0);
            cntacc[mt2] = __builtin_amdgcn_mfma_f32_16x16x32_bf16(a1, one8.v, cntacc[mt2], 0, 0, 0);
            #pragma unroll
            for (int dt = 0; dt < 8; ++dt) {
                const int drow = dt * 16 + l15;
                const int dx = (drow >> 3) & 7;
                const unsigned short* xp = &sXT[drow * 64];
                bf16x8 b0 = *reinterpret_cast<const bf16x8*>(
                    &xp[((quad ^ dx) & 7) * 8]);
                bf16x8 b1 = *reinterpret_cast<const bf16x8*>(
                    &xp[(((4 + quad) ^ dx) & 7) * 8]);
                eacc[mt2][dt] = __builtin_amdgcn_mfma_f32_16x16x32_bf16(a0, b0, eacc[mt2][dt], 0, 0, 0);
                eacc[mt2][dt] = __builtin_amdgcn_mfma_f32_16x16x32_bf16(a1, b1, eacc[mt2][dt], 0, 0, 0);
            }
        }
    }

    // ---- epilogue: bf16 partial (E_part - count*C) to private ws slice ----
    // cntacc[mt2][r] holds count for cw = wave*32+mt2*16+quad*4+r (all l15 lanes)
    unsigned short* P = Pg + (size_t)bid * (NK * ND);
    #pragma unroll
    for (int mt2 = 0; mt2 < 2; ++mt2) {
        #pragma unroll
        for (int r = 0; r < 4; ++r) {
            const int cw = wave * 32 + mt2 * 16 + quad * 4 + r;
            const float cc = cntacc[mt2][r];
            const float* crow = Cg + cw * ND;
            #pragma unroll
            for (int dt = 0; dt < 8; ++dt) {
                const int d = dt * 16 + l15;
                *reinterpret_cast<__bf16*>(&P[cw * ND + d]) =
                    (__bf16)(eacc[mt2][dt][r] - cc * crow[d]);
            }
        }
    }
}

// ---------------- kernel 2: partial reduction ----------------
__global__ __launch_bounds__(256) void vq_reduce(
    const unsigned short* __restrict__ Pg, float* __restrict__ Eg)
{
    const int g  = blockIdx.x * 256 + threadIdx.x;   // 0..32767
    const int b  = g >> 12;                          // 4096 quad-groups per b
    const int i4 = g & 4095;
    const unsigned short* base = Pg + (size_t)(b * BPB) * (NK * ND) + i4 * 4;
    float a0 = 0.f, a1 = 0.f, a2 = 0.f, a3 = 0.f;
    #pragma unroll 8
    for (int j = 0; j < BPB; ++j) {
        ushort4 v = *reinterpret_cast<const ushort4*>(base + (size_t)j * (NK * ND));
        a0 += bf2f(v.x); a1 += bf2f(v.y); a2 += bf2f(v.z); a3 += bf2f(v.w);
    }
    float4 o; o.x = a0; o.y = a1; o.z = a2; o.w = a3;
    *reinterpret_cast<float4*>(Eg + (size_t)b * (NK * ND) + i4 * 4) = o;
}

extern "C" void kernel_launch(void* const* d_in, const int* in_sizes, int n_in,
                              void* d_out, int out_size, void* d_ws, size_t ws_size,
                              hipStream_t stream) {
    const float* X = (const float*)d_in[0];
    const float* C = (const float*)d_in[1];
    const float* S = (const float*)d_in[2];
    float* E = (float*)d_out;
    (void)n_in; (void)in_sizes; (void)out_size; (void)ws_size;

    // ws layout: bf16 partials, 512 * 16384 u16 = 16 MiB.
    unsigned short* P = (unsigned short*)d_ws;

    hipLaunchKernelGGL(vq_main,   dim3(512), dim3(256), 0, stream, X, C, S, P);
    hipLaunchKernelGGL(vq_reduce, dim3(128), dim3(256), 0, stream, P, E);
}

// Round 8
// 114.911 us; speedup vs baseline: 1.1150x; 1.1150x over previous
//
#include <hip/hip_runtime.h>

// Soft VQ encoding, fused bf16-MFMA implementation. Round 8.
//   X:(8,16384,128) fp32, C:(128,128) fp32, S:(128) fp32 -> E:(8,128,128) fp32
// r7 post-mortem (reverted): (a) chs C-frag hoist pushed arch VGPRs >128 ->
// static cap/2 split spilled (VGPR_Count=128=cap/2, +12MB scratch WRITE);
// (b) unpadded stride-64 + XOR granule swizzle collapsed to 2 distinct
// granules on the sAt scatter (8-way conflicts) -> SQ_LDS_BANK_CONFLICT
// 2.23M->3.67M. r8 = r6 base (pad-72 layouts, no hoist, 115us) plus:
//   (1) no-max softmax (safe: S<=0 => D<=0 => exp in (0,1]; r7 absmax same).
//   (2) matmul2 loop-swap: dt-outer, a-frags hoisted (4 b128) -> b-frag
//       reads halved 32->16 b128/wave/chunk on the dominant LDS pipe.
//       (+~10 arch regs; WRITE>20MB = spill tripwire -> drop hoist.)
//   (3) vq_reduce 512x64 instead of 128x256 (same threads, all CUs covered).
// 2 kernels: vq_main<<<512,256>>> (TT=4 chunks of 64 rows, bf16 partials to
// private ws slices), vq_reduce<<<512,64>>> (fp32-sum 64 partials -> d_out).

#define NN   16384
#define ND   128
#define NK   128
#define NC   64        // rows per chunk
#define TT   4         // chunks per block
#define BPB  64        // blocks per batch (grid = 8*BPB = 512)
#define CBP  136       // sCb row stride (bf16 elems), 272B -> b128-aligned, 2-way banks
#define XTP  72        // X^T LDS row stride, 144B (stride%32banks=4 -> spreads rows)
#define ATP  72        // A^T LDS row stride, 144B

typedef __bf16 bf16x8 __attribute__((ext_vector_type(8)));
typedef float  f32x4  __attribute__((ext_vector_type(4)));

union CU  { __bf16 b[8]; unsigned short u[8]; bf16x8 v; };
union HH4 { __bf16 b[4]; ushort4 s; };

__device__ __forceinline__ float bf2f(unsigned short u) {
    return __uint_as_float(((unsigned int)u) << 16);
}

// ---------------- kernel 1: fused main ----------------
__global__ __launch_bounds__(256, 2) void vq_main(
    const float* __restrict__ Xg, const float* __restrict__ Cg,
    const float* __restrict__ Sg, unsigned short* __restrict__ Pg)
{
    __shared__ __align__(16) unsigned short sCb[NK * CBP];   // 34816 B
    __shared__ __align__(16) unsigned short sXT[ND * XTP];   // 18432 B
    __shared__ __align__(16) unsigned short sAt[NK * ATP];   // 18432 B
    __shared__ __align__(16) float2 sST[NK];                 // 1 KB
    __shared__ __align__(16) float  sC2[NK];                 // 512 B

    const int tid  = threadIdx.x;
    const int lane = tid & 63;
    const int wave = tid >> 6;
    const int l15  = lane & 15;
    const int quad = lane >> 4;
    const int bid  = blockIdx.x;
    const int b    = bid >> 6;        // batch
    const int bg   = bid & (BPB - 1); // block-in-batch

    // ---- prologue: stage C -> bf16 LDS, C2 row sums, ST = {S, S*C2} ----
    #pragma unroll
    for (int it = 0; it < 16; ++it) {
        int flat = it * 256 + tid;
        int row  = flat >> 5;          // 0..127
        int c4   = flat & 31;
        float4 v = reinterpret_cast<const float4*>(Cg)[row * 32 + c4];
        HH4 h;
        h.b[0] = (__bf16)v.x; h.b[1] = (__bf16)v.y;
        h.b[2] = (__bf16)v.z; h.b[3] = (__bf16)v.w;
        *reinterpret_cast<ushort4*>(&sCb[row * CBP + c4 * 4]) = h.s;
        float ss = v.x*v.x + v.y*v.y + v.z*v.z + v.w*v.w;
        ss += __shfl_xor(ss, 1);
        ss += __shfl_xor(ss, 2);
        ss += __shfl_xor(ss, 4);
        ss += __shfl_xor(ss, 8);
        ss += __shfl_xor(ss, 16);
        if ((lane & 31) == 0) sC2[row] = ss;
    }
    __syncthreads();
    if (tid < NK) {
        float s = Sg[tid];
        sST[tid] = make_float2(s, s * sC2[tid]);
    }
    // (barrier (A) of chunk 0 orders sST before first softmax use)

    f32x4 eacc[2][8];
    #pragma unroll
    for (int i = 0; i < 2; ++i)
        #pragma unroll
        for (int j = 0; j < 8; ++j)
            eacc[i][j] = (f32x4){0.f, 0.f, 0.f, 0.f};
    f32x4 cntacc[2];
    cntacc[0] = (f32x4){0.f, 0.f, 0.f, 0.f};
    cntacc[1] = (f32x4){0.f, 0.f, 0.f, 0.f};

    CU one8;
    #pragma unroll
    for (int j = 0; j < 8; ++j) one8.u[j] = 0x3F80;  // bf16 1.0

    const float* Xb = Xg + (size_t)b * (NN * ND);
    const int rloc = wave * 16 + l15;   // chunk-local row this lane stages

    // software pipeline: raw[] holds next chunk's ks=0,1 halves (4 float4)
    float4 raw[4];
    {
        const float* rp0 = Xb + (size_t)(bg * TT * NC + rloc) * ND;
        raw[0] = *reinterpret_cast<const float4*>(rp0 + quad * 8);
        raw[1] = *reinterpret_cast<const float4*>(rp0 + quad * 8 + 4);
        raw[2] = *reinterpret_cast<const float4*>(rp0 + 32 + quad * 8);
        raw[3] = *reinterpret_cast<const float4*>(rp0 + 32 + quad * 8 + 4);
    }

    #pragma unroll 1
    for (int t = 0; t < TT; ++t) {
        const int chunk = bg * TT + t;
        const float* rp = Xb + (size_t)(chunk * NC + rloc) * ND;

        // ---- ks=2,3 loads issued first (latency overlapped w/ conversions) ----
        float4 va2 = *reinterpret_cast<const float4*>(rp + 64 + quad * 8);
        float4 vb2 = *reinterpret_cast<const float4*>(rp + 64 + quad * 8 + 4);
        float4 va3 = *reinterpret_cast<const float4*>(rp + 96 + quad * 8);
        float4 vb3 = *reinterpret_cast<const float4*>(rp + 96 + quad * 8 + 4);

        CU cu[4];
        float x2 = 0.f;
        #pragma unroll
        for (int ks = 0; ks < 2; ++ks) {
            float4 va = raw[ks * 2], vb = raw[ks * 2 + 1];
            x2 += va.x*va.x + va.y*va.y + va.z*va.z + va.w*va.w;
            x2 += vb.x*vb.x + vb.y*vb.y + vb.z*vb.z + vb.w*vb.w;
            cu[ks].b[0] = (__bf16)va.x; cu[ks].b[1] = (__bf16)va.y;
            cu[ks].b[2] = (__bf16)va.z; cu[ks].b[3] = (__bf16)va.w;
            cu[ks].b[4] = (__bf16)vb.x; cu[ks].b[5] = (__bf16)vb.y;
            cu[ks].b[6] = (__bf16)vb.z; cu[ks].b[7] = (__bf16)vb.w;
        }
        {
            x2 += va2.x*va2.x + va2.y*va2.y + va2.z*va2.z + va2.w*va2.w;
            x2 += vb2.x*vb2.x + vb2.y*vb2.y + vb2.z*vb2.z + vb2.w*vb2.w;
            cu[2].b[0] = (__bf16)va2.x; cu[2].b[1] = (__bf16)va2.y;
            cu[2].b[2] = (__bf16)va2.z; cu[2].b[3] = (__bf16)va2.w;
            cu[2].b[4] = (__bf16)vb2.x; cu[2].b[5] = (__bf16)vb2.y;
            cu[2].b[6] = (__bf16)vb2.z; cu[2].b[7] = (__bf16)vb2.w;
            x2 += va3.x*va3.x + va3.y*va3.y + va3.z*va3.z + va3.w*va3.w;
            x2 += vb3.x*vb3.x + vb3.y*vb3.y + vb3.z*vb3.z + vb3.w*vb3.w;
            cu[3].b[0] = (__bf16)va3.x; cu[3].b[1] = (__bf16)va3.y;
            cu[3].b[2] = (__bf16)va3.z; cu[3].b[3] = (__bf16)va3.w;
            cu[3].b[4] = (__bf16)vb3.x; cu[3].b[5] = (__bf16)vb3.y;
            cu[3].b[6] = (__bf16)vb3.z; cu[3].b[7] = (__bf16)vb3.w;
        }
        x2 += __shfl_xor(x2, 16);
        x2 += __shfl_xor(x2, 32);       // full X2 of row (chunk*64 + rloc)

        __syncthreads();                // (A) prev chunk's matmul2 reads done

        // ---- prefetch next chunk's ks=0,1 (in flight until barrier B) ----
        if (t + 1 < TT) {
            const float* rpn = rp + (size_t)NC * ND;
            raw[0] = *reinterpret_cast<const float4*>(rpn + quad * 8);
            raw[1] = *reinterpret_cast<const float4*>(rpn + quad * 8 + 4);
            raw[2] = *reinterpret_cast<const float4*>(rpn + 32 + quad * 8);
            raw[3] = *reinterpret_cast<const float4*>(rpn + 32 + quad * 8 + 4);
        }

        // ---- scatter X^T (swizzled to dodge bank conflicts) ----
        #pragma unroll
        for (int ks = 0; ks < 4; ++ks) {
            #pragma unroll
            for (int j = 0; j < 8; ++j) {
                int d  = ks * 32 + quad * 8 + j;
                int rs = rloc ^ (((d >> 3) & 3) << 3);
                sXT[d * XTP + rs] = cu[ks].u[j];
            }
        }

        // ---- matmul1: DT[cw][n] = C x X^T (A-frags from LDS sCb) ----
        f32x4 dacc[8];
        #pragma unroll
        for (int mt = 0; mt < 8; ++mt) {
            f32x4 acc = (f32x4){0.f, 0.f, 0.f, 0.f};
            #pragma unroll
            for (int ks = 0; ks < 4; ++ks) {
                bf16x8 af = *reinterpret_cast<const bf16x8*>(
                    &sCb[(mt * 16 + l15) * CBP + ks * 32 + quad * 8]);
                acc = __builtin_amdgcn_mfma_f32_16x16x32_bf16(af, cu[ks].v, acc, 0, 0, 0);
            }
            dacc[mt] = acc;
        }

        // ---- softmax over cw, NO max pass (S<=0 => D<=0 => exp in (0,1]) ----
        float ls = 0.f;
        #pragma unroll
        for (int mt = 0; mt < 8; ++mt) {
            float4 s01 = *reinterpret_cast<const float4*>(&sST[mt * 16 + quad * 4]);
            float4 s23 = *reinterpret_cast<const float4*>(&sST[mt * 16 + quad * 4 + 2]);
            float e0 = __expf(s01.x * fmaf(-2.f, dacc[mt][0], x2) + s01.y);
            float e1 = __expf(s01.z * fmaf(-2.f, dacc[mt][1], x2) + s01.w);
            float e2 = __expf(s23.x * fmaf(-2.f, dacc[mt][2], x2) + s23.y);
            float e3 = __expf(s23.z * fmaf(-2.f, dacc[mt][3], x2) + s23.w);
            dacc[mt][0] = e0; dacc[mt][1] = e1;
            dacc[mt][2] = e2; dacc[mt][3] = e3;
            ls += (e0 + e1) + (e2 + e3);
        }
        ls += __shfl_xor(ls, 16);
        ls += __shfl_xor(ls, 32);
        const float inv = 1.0f / ls;

        // ---- A -> LDS (A-operand layout: rows=cw, cols=n) ----
        #pragma unroll
        for (int mt = 0; mt < 8; ++mt) {
            #pragma unroll
            for (int r = 0; r < 4; ++r) {
                float a = dacc[mt][r] * inv;
                *reinterpret_cast<__bf16*>(
                    &sAt[(mt * 16 + quad * 4 + r) * ATP + rloc]) = (__bf16)a;
            }
        }

        __syncthreads();                // (B) X^T and A^T visible to all waves

        // ---- matmul2: E[cw][d] += A x X, dt-outer so each b-frag is read
        //      ONCE and reused for both mt2 (b128 reads 32 -> 16/wave/chunk).
        bf16x8 a0[2], a1[2];
        #pragma unroll
        for (int mt2 = 0; mt2 < 2; ++mt2) {
            const int cwrow = wave * 32 + mt2 * 16 + l15;
            a0[mt2] = *reinterpret_cast<const bf16x8*>(&sAt[cwrow * ATP + quad * 8]);
            a1[mt2] = *reinterpret_cast<const bf16x8*>(&sAt[cwrow * ATP + 32 + quad * 8]);
            // count[cw] += sum_n A[cw][n]: B = ones -> D[row][col] indep of col
            cntacc[mt2] = __builtin_amdgcn_mfma_f32_16x16x32_bf16(a0[mt2], one8.v, cntacc[mt2], 0, 0, 0);
            cntacc[mt2] = __builtin_amdgcn_mfma_f32_16x16x32_bf16(a1[mt2], one8.v, cntacc[mt2], 0, 0, 0);
        }
        #pragma unroll
        for (int dt = 0; dt < 8; ++dt) {
            const int drow = dt * 16 + l15;
            const int sw = ((drow >> 3) & 3) << 3;
            const unsigned short* xp = &sXT[drow * XTP];
            bf16x8 b0 = *reinterpret_cast<const bf16x8*>(&xp[(quad * 8) ^ sw]);
            bf16x8 b1 = *reinterpret_cast<const bf16x8*>(&xp[(32 + quad * 8) ^ sw]);
            #pragma unroll
            for (int mt2 = 0; mt2 < 2; ++mt2) {
                eacc[mt2][dt] = __builtin_amdgcn_mfma_f32_16x16x32_bf16(a0[mt2], b0, eacc[mt2][dt], 0, 0, 0);
                eacc[mt2][dt] = __builtin_amdgcn_mfma_f32_16x16x32_bf16(a1[mt2], b1, eacc[mt2][dt], 0, 0, 0);
            }
        }
    }

    // ---- epilogue: bf16 partial (E_part - count*C) to private ws slice ----
    // cntacc[mt2][r] holds count for cw = wave*32+mt2*16+quad*4+r (all l15 lanes)
    unsigned short* P = Pg + (size_t)bid * (NK * ND);
    #pragma unroll
    for (int mt2 = 0; mt2 < 2; ++mt2) {
        #pragma unroll
        for (int r = 0; r < 4; ++r) {
            const int cw = wave * 32 + mt2 * 16 + quad * 4 + r;
            const float cc = cntacc[mt2][r];
            const float* crow = Cg + cw * ND;
            #pragma unroll
            for (int dt = 0; dt < 8; ++dt) {
                const int d = dt * 16 + l15;
                *reinterpret_cast<__bf16*>(&P[cw * ND + d]) =
                    (__bf16)(eacc[mt2][dt][r] - cc * crow[d]);
            }
        }
    }
}

// ---------------- kernel 2: partial reduction ----------------
__global__ __launch_bounds__(64) void vq_reduce(
    const unsigned short* __restrict__ Pg, float* __restrict__ Eg)
{
    const int g  = blockIdx.x * 64 + threadIdx.x;    // 0..32767
    const int b  = g >> 12;                          // 4096 quad-groups per b
    const int i4 = g & 4095;
    const unsigned short* base = Pg + (size_t)(b * BPB) * (NK * ND) + i4 * 4;
    float a0 = 0.f, a1 = 0.f, a2 = 0.f, a3 = 0.f;
    #pragma unroll 8
    for (int j = 0; j < BPB; ++j) {
        ushort4 v = *reinterpret_cast<const ushort4*>(base + (size_t)j * (NK * ND));
        a0 += bf2f(v.x); a1 += bf2f(v.y); a2 += bf2f(v.z); a3 += bf2f(v.w);
    }
    float4 o; o.x = a0; o.y = a1; o.z = a2; o.w = a3;
    *reinterpret_cast<float4*>(Eg + (size_t)b * (NK * ND) + i4 * 4) = o;
}

extern "C" void kernel_launch(void* const* d_in, const int* in_sizes, int n_in,
                              void* d_out, int out_size, void* d_ws, size_t ws_size,
                              hipStream_t stream) {
    const float* X = (const float*)d_in[0];
    const float* C = (const float*)d_in[1];
    const float* S = (const float*)d_in[2];
    float* E = (float*)d_out;
    (void)n_in; (void)in_sizes; (void)out_size; (void)ws_size;

    // ws layout: bf16 partials, 512 * 16384 u16 = 16 MiB.
    unsigned short* P = (unsigned short*)d_ws;

    hipLaunchKernelGGL(vq_main,   dim3(512), dim3(256), 0, stream, X, C, S, P);
    hipLaunchKernelGGL(vq_reduce, dim3(512), dim3(64),  0, stream, P, E);
}